// Round 8
// baseline (261.651 us; speedup 1.0000x reference)
//
#include <hip/hip_runtime.h>
#include <math.h>

typedef _Float16 f16;
typedef _Float16 f16x2 __attribute__((ext_vector_type(2)));
typedef _Float16 f16x4 __attribute__((ext_vector_type(4)));
typedef _Float16 f16x8 __attribute__((ext_vector_type(8)));
typedef __fp16 h16x2 __attribute__((ext_vector_type(2)));
typedef float f32x4 __attribute__((ext_vector_type(4)));
typedef float f32x16 __attribute__((ext_vector_type(16)));

#define N_TOK 2048
#define C_DIM 1024
#define E_NUM 8
#define F_DIM 2048
#define BM 256

// ws layout (bytes)
#define WS_COUNTS    0
#define WS_OFFSETS   64
#define WS_CURSOR    192
#define WS_TOPI      256
#define WS_TOPW      (WS_TOPI + 16384)
#define WS_ROWS      (WS_TOPW + 16384)
#define WS_SLOT      (WS_ROWS + 16384)
#define WS_X16       (1ull << 20)     // 4 MB
#define WS_H         (6ull << 20)     // 16.8 MB
#define WS_Y0        (23ull << 20)    // 8.4 MB
#define WS_Y1        (32ull << 20)    // 8.4 MB
#define WS_W1T       (48ull << 20)    // 32 MB f16 [e][f][k]
#define WS_W3T       (80ull << 20)    // 32 MB
#define WS_W2T       (112ull << 20)   // 32 MB f16 [e][c][k]

__device__ __forceinline__ void glds16(const void* g, void* l) {
  __builtin_amdgcn_global_load_lds((const __attribute__((address_space(1))) void*)g,
                                   (__attribute__((address_space(3))) void*)l, 16, 0, 0);
}

__device__ __forceinline__ f16x2 pkrtz(float a, float b) {
  union { h16x2 h; f16x2 f; } u;
  u.h = __builtin_amdgcn_cvt_pkrtz(a, b);
  return u.f;
}

// ---------------- x fp32 -> fp16 ----------------
__global__ void cvtx_kernel(const float* __restrict__ x, f16* __restrict__ x16) {
  int i = (blockIdx.x * 256 + threadIdx.x) * 8;
  f32x4 a = *(const f32x4*)(x + i);
  f32x4 b = *(const f32x4*)(x + i + 4);
  union { f16x8 v; f16x2 h[4]; } u;
  u.h[0] = pkrtz(a[0], a[1]);
  u.h[1] = pkrtz(a[2], a[3]);
  u.h[2] = pkrtz(b[0], b[1]);
  u.h[3] = pkrtz(b[2], b[3]);
  *(f16x8*)(x16 + i) = u.v;
}

// ---------------- weight transpose+convert: [e][k][f] f32 -> [e][f][k] f16 ----------------
// 128x128 tiles; LDS [128][132] f16 (pad: 8B-aligned b64 writes, conflict-light).
__global__ void wt_kernel(const float* __restrict__ w1, const float* __restrict__ w3,
                          const float* __restrict__ w2,
                          f16* __restrict__ w1t, f16* __restrict__ w3t, f16* __restrict__ w2t) {
  __shared__ __align__(16) f16 T[128 * 132];
  int tid = blockIdx.x;
  int m = tid >> 10;          // 0=w1 1=w3 2=w2
  int r = tid & 1023;
  int e = r >> 7;
  int tl = r & 127;
  const float* src; f16* dst; int K, Fd, kt, ft;
  if (m == 2) { K = F_DIM; Fd = C_DIM; kt = tl >> 3; ft = tl & 7; src = w2; dst = w2t; }
  else        { K = C_DIM; Fd = F_DIM; kt = tl >> 4; ft = tl & 15; src = (m ? w3 : w1); dst = (m ? w3t : w1t); }
  src += ((size_t)e * K + kt * 128) * Fd + ft * 128;
  dst += ((size_t)e * Fd + ft * 128) * K + kt * 128;
  int t = threadIdx.x;
  int rr = t >> 5, c4 = (t & 31) * 4;
#pragma unroll
  for (int it = 0; it < 16; ++it) {
    int k = it * 8 + rr;
    f32x4 v = *(const f32x4*)(src + (size_t)k * Fd + c4);
    union { f16x4 q; f16x2 h[2]; } u;
    u.h[0] = pkrtz(v[0], v[1]); u.h[1] = pkrtz(v[2], v[3]);
    *(f16x4*)&T[k * 132 + c4] = u.q;
  }
  __syncthreads();
  int f = t >> 1, kh = t & 1;
#pragma unroll
  for (int j8 = 0; j8 < 8; ++j8) {
    union { f16x8 v; f16 s[8]; } u;
#pragma unroll
    for (int jj = 0; jj < 8; ++jj) u.s[jj] = T[(kh * 64 + j8 * 8 + jj) * 132 + f];
    *(f16x8*)(dst + (size_t)f * K + kh * 64 + j8 * 8) = u.v;
  }
}

// ---------------- router ----------------
__global__ void router_kernel(const float* __restrict__ x, const float* __restrict__ Wr,
                              int* counts, int* topi, float* topw) {
  int tok = blockIdx.x * 4 + (threadIdx.x >> 6);
  int lane = threadIdx.x & 63;
  const float* xr = x + (size_t)tok * C_DIM;
  float xv[16];
#pragma unroll
  for (int i = 0; i < 16; ++i) xv[i] = xr[i * 64 + lane];
  float logit[E_NUM];
#pragma unroll
  for (int e = 0; e < E_NUM; ++e) {
    const float* wr = Wr + (size_t)e * C_DIM;
    float acc = 0.f;
#pragma unroll
    for (int i = 0; i < 16; ++i) acc += xv[i] * wr[i * 64 + lane];
#pragma unroll
    for (int s = 1; s < 64; s <<= 1) acc += __shfl_xor(acc, s, 64);
    logit[e] = acc;
  }
  if (lane == 0) {
    float m = logit[0];
#pragma unroll
    for (int e = 1; e < E_NUM; ++e) m = fmaxf(m, logit[e]);
    float p[E_NUM];
#pragma unroll
    for (int e = 0; e < E_NUM; ++e) p[e] = expf(logit[e] - m);
    float p0 = -1.f, p1 = -1.f;
    int i0 = 0, i1 = 0;
#pragma unroll
    for (int e = 0; e < E_NUM; ++e) {
      float v = p[e];
      if (v > p0) { p1 = p0; i1 = i0; p0 = v; i0 = e; }
      else if (v > p1) { p1 = v; i1 = e; }
    }
    float inv = 1.f / (p0 + p1);
    topi[2 * tok] = i0; topi[2 * tok + 1] = i1;
    topw[2 * tok] = p0 * inv; topw[2 * tok + 1] = p1 * inv;
    atomicAdd(&counts[i0], 1);
    atomicAdd(&counts[i1], 1);
  }
}

// ---------------- scan ----------------
__global__ void scan_kernel(const int* counts, int* offsets, int* cursor) {
  if (threadIdx.x == 0) {
    int o = 0;
    for (int e = 0; e < E_NUM; ++e) {
      offsets[e] = o; cursor[e] = o;
      o += counts[e];
    }
    offsets[E_NUM] = o;
  }
}

// ---------------- scatter ----------------
__global__ void scatter_kernel(const int* __restrict__ topi, int* cursor,
                               int* rows_perm, int* slot_of) {
  int n = blockIdx.x * blockDim.x + threadIdx.x;
  if (n >= N_TOK) return;
#pragma unroll
  for (int k = 0; k < 2; ++k) {
    int e = topi[2 * n + k];
    int pos = atomicAdd(&cursor[e], 1);
    rows_perm[pos] = n;
    slot_of[2 * n + k] = pos;
  }
}

#define ROT3(P0, P1, P2) { f16* _t = P0; P0 = P1; P1 = P2; P2 = _t; }

// ================= up-proj: h = silu(x@w1)*(x@w3) =================
// 256x128 tile, BK=32, 8 waves, 32x32x16 MFMA. Pure-glds staging (pre-swizzled
// sources), triple-buffered LDS, race-free order: vmcnt -> barrier -> issue.
#define UP_MFMA()                                                                \
  do {                                                                           \
    f16x8 a[2][2], b[2][2];                                                      \
    _Pragma("unroll") for (int mi = 0; mi < 2; ++mi)                             \
      _Pragma("unroll") for (int kk = 0; kk < 2; ++kk) {                         \
        int row = wr + mi * 32 + ln31;                                           \
        int cell = kk * 2 + fh;                                                  \
        a[mi][kk] = *(const f16x8*)&a_c[row * 32 + (cell ^ ((row >> 1) & 3)) * 8]; } \
    _Pragma("unroll") for (int ni = 0; ni < 2; ++ni)                             \
      _Pragma("unroll") for (int kk = 0; kk < 2; ++kk) {                         \
        int col = wc + ni * 32 + ln31;                                           \
        int cell = kk * 2 + fh;                                                  \
        b[ni][kk] = *(const f16x8*)&b1_c[col * 32 + (cell ^ ((col >> 1) & 3)) * 8]; } \
    __builtin_amdgcn_s_setprio(1);                                               \
    _Pragma("unroll") for (int kk = 0; kk < 2; ++kk)                             \
      _Pragma("unroll") for (int mi = 0; mi < 2; ++mi)                           \
        _Pragma("unroll") for (int ni = 0; ni < 2; ++ni)                         \
          acc1[mi][ni] = __builtin_amdgcn_mfma_f32_32x32x16_f16(a[mi][kk], b[ni][kk], acc1[mi][ni], 0, 0, 0); \
    __builtin_amdgcn_s_setprio(0);                                               \
    _Pragma("unroll") for (int ni = 0; ni < 2; ++ni)                             \
      _Pragma("unroll") for (int kk = 0; kk < 2; ++kk) {                         \
        int col = wc + ni * 32 + ln31;                                           \
        int cell = kk * 2 + fh;                                                  \
        b[ni][kk] = *(const f16x8*)&b3_c[col * 32 + (cell ^ ((col >> 1) & 3)) * 8]; } \
    __builtin_amdgcn_s_setprio(1);                                               \
    _Pragma("unroll") for (int kk = 0; kk < 2; ++kk)                             \
      _Pragma("unroll") for (int mi = 0; mi < 2; ++mi)                           \
        _Pragma("unroll") for (int ni = 0; ni < 2; ++ni)                         \
          acc3[mi][ni] = __builtin_amdgcn_mfma_f32_32x32x16_f16(a[mi][kk], b[ni][kk], acc3[mi][ni], 0, 0, 0); \
    __builtin_amdgcn_s_setprio(0);                                               \
  } while (0)

__launch_bounds__(512, 2)
__global__ void upproj_kernel(const f16* __restrict__ x16,
                              const f16* __restrict__ w1t,
                              const f16* __restrict__ w3t,
                              const int* __restrict__ counts,
                              const int* __restrict__ offsets,
                              const int* __restrict__ rows_perm,
                              f16* __restrict__ h_buf) {
  __shared__ __align__(16) f16 A_lds[3][BM * 32];
  __shared__ __align__(16) f16 B1_lds[3][128 * 32];
  __shared__ __align__(16) f16 B3_lds[3][128 * 32];

  int bid = blockIdx.x;
  int e = bid & 7;            // expert-locked XCD
  int slot = bid >> 3;        // 0..127
  int fidx = slot & 15;       // valid blocks dense at low bids (1/CU typical)
  int tile = slot >> 4;
  int cnt = counts[e];
  if (tile * BM >= cnt) return;
  int row0 = tile * BM;
  int off = offsets[e];
  int f0 = fidx * 128;
  int t = threadIdx.x, wid = t >> 6, lane = t & 63;
  int ln31 = lane & 31, fh = lane >> 5;

  // A sources (gathered x rows), pre-swizzled cell on the global side
  const f16* asrc[2];
#pragma unroll
  for (int p = 0; p < 2; ++p) {
    int c = p * 512 + t;
    int row = c >> 2, cc = c & 3;
    int lr = row0 + row; if (lr > cnt - 1) lr = cnt - 1;
    int g = rows_perm[off + lr];
    asrc[p] = x16 + (size_t)g * C_DIM + 8 * (cc ^ ((row >> 1) & 3));
  }
  // B sources: w1t/w3t rows (f-major, k-contiguous), pre-swizzled
  int bcol = t >> 2, bcc = t & 3;
  int bswz = 8 * (bcc ^ ((bcol >> 1) & 3));
  const f16* b1src = w1t + (size_t)e * F_DIM * C_DIM + (size_t)(f0 + bcol) * C_DIM + bswz;
  const f16* b3src = w3t + (size_t)e * F_DIM * C_DIM + (size_t)(f0 + bcol) * C_DIM + bswz;

  f32x16 acc1[2][2] = {};
  f32x16 acc3[2][2] = {};
  int wr = (wid >> 1) * 64, wc = (wid & 1) * 64;

  f16 *a_c = &A_lds[0][0], *a_n = &A_lds[1][0], *a_f = &A_lds[2][0];
  f16 *b1_c = &B1_lds[0][0], *b1_n = &B1_lds[1][0], *b1_f = &B1_lds[2][0];
  f16 *b3_c = &B3_lds[0][0], *b3_n = &B3_lds[1][0], *b3_f = &B3_lds[2][0];

  // prologue: issue steps 0 and 1 (4 glds each, in step order)
  glds16(asrc[0], a_c + wid * 512);
  glds16(asrc[1], a_c + (8 + wid) * 512);
  glds16(b1src, b1_c + wid * 512);
  glds16(b3src, b3_c + wid * 512);
  glds16(asrc[0] + 32, a_n + wid * 512);
  glds16(asrc[1] + 32, a_n + (8 + wid) * 512);
  glds16(b1src + 32, b1_n + wid * 512);
  glds16(b3src + 32, b3_n + wid * 512);

  for (int tt = 0; tt < 30; ++tt) {
    asm volatile("s_waitcnt vmcnt(4)" ::: "memory");   // my step-t glds done
    __builtin_amdgcn_s_barrier();                      // => all waves' step-t done
    asm volatile("" ::: "memory");
    int kn = (tt + 2) * 32;
    glds16(asrc[0] + kn, a_f + wid * 512);
    glds16(asrc[1] + kn, a_f + (8 + wid) * 512);
    glds16(b1src + kn, b1_f + wid * 512);
    glds16(b3src + kn, b3_f + wid * 512);
    UP_MFMA();
    ROT3(a_c, a_n, a_f); ROT3(b1_c, b1_n, b1_f); ROT3(b3_c, b3_n, b3_f);
  }
  asm volatile("s_waitcnt vmcnt(4)" ::: "memory");
  __builtin_amdgcn_s_barrier();
  asm volatile("" ::: "memory");
  UP_MFMA();
  ROT3(a_c, a_n, a_f); ROT3(b1_c, b1_n, b1_f); ROT3(b3_c, b3_n, b3_f);
  asm volatile("s_waitcnt vmcnt(0)" ::: "memory");
  __builtin_amdgcn_s_barrier();
  asm volatile("" ::: "memory");
  UP_MFMA();

#pragma unroll
  for (int mi = 0; mi < 2; ++mi)
#pragma unroll
    for (int ni = 0; ni < 2; ++ni)
#pragma unroll
      for (int i = 0; i < 16; ++i) {
        int rr = (i & 3) + 8 * (i >> 2) + 4 * fh;
        int lr = row0 + wr + mi * 32 + rr;
        if (lr < cnt) {
          float v1 = acc1[mi][ni][i], v3 = acc3[mi][ni][i];
          float hval = v1 / (1.f + expf(-v1)) * v3;
          h_buf[(size_t)(off + lr) * F_DIM + f0 + wc + ni * 32 + ln31] = (f16)hval;
        }
      }
}

// ================= down-proj =================
#define DN_MFMA()                                                                \
  do {                                                                           \
    f16x8 a[2][2], b[2][2];                                                      \
    _Pragma("unroll") for (int mi = 0; mi < 2; ++mi)                             \
      _Pragma("unroll") for (int kk = 0; kk < 2; ++kk) {                         \
        int row = wr + mi * 32 + ln31;                                           \
        int cell = kk * 2 + fh;                                                  \
        a[mi][kk] = *(const f16x8*)&a_c[row * 32 + (cell ^ ((row >> 1) & 3)) * 8]; } \
    _Pragma("unroll") for (int ni = 0; ni < 2; ++ni)                             \
      _Pragma("unroll") for (int kk = 0; kk < 2; ++kk) {                         \
        int col = wc + ni * 32 + ln31;                                           \
        int cell = kk * 2 + fh;                                                  \
        b[ni][kk] = *(const f16x8*)&b_c[col * 32 + (cell ^ ((col >> 1) & 3)) * 8]; } \
    __builtin_amdgcn_s_setprio(1);                                               \
    _Pragma("unroll") for (int kk = 0; kk < 2; ++kk)                             \
      _Pragma("unroll") for (int mi = 0; mi < 2; ++mi)                           \
        _Pragma("unroll") for (int ni = 0; ni < 2; ++ni)                         \
          acc[mi][ni] = __builtin_amdgcn_mfma_f32_32x32x16_f16(a[mi][kk], b[ni][kk], acc[mi][ni], 0, 0, 0); \
    __builtin_amdgcn_s_setprio(0);                                               \
  } while (0)

__launch_bounds__(512, 2)
__global__ void downproj_kernel(const f16* __restrict__ h_buf,
                                const f16* __restrict__ w2t,
                                const int* __restrict__ counts,
                                const int* __restrict__ offsets,
                                f16* __restrict__ y0,
                                f16* __restrict__ y1) {
  __shared__ __align__(16) f16 A_lds[3][BM * 32];
  __shared__ __align__(16) f16 B_lds[3][128 * 32];

  int bid = blockIdx.x;
  int e = bid & 7;
  int slot = bid >> 3;         // 0..127
  int cidx = slot & 7;
  int kh = (slot >> 3) & 1;
  int tile = slot >> 4;
  int cnt = counts[e];
  if (tile * BM >= cnt) return;
  f16* yb = kh ? y1 : y0;
  int row0 = tile * BM;
  int off = offsets[e];
  int c0 = cidx * 128;
  int t = threadIdx.x, wid = t >> 6, lane = t & 63;
  int ln31 = lane & 31, fh = lane >> 5;

  const f16* asrc[2];
#pragma unroll
  for (int p = 0; p < 2; ++p) {
    int c = p * 512 + t;
    int row = c >> 2, cc = c & 3;
    int lr = row0 + row; if (lr > cnt - 1) lr = cnt - 1;
    asrc[p] = h_buf + (size_t)(off + lr) * F_DIM + kh * 1024 + 8 * (cc ^ ((row >> 1) & 3));
  }
  int bcol = t >> 2, bcc = t & 3;
  const f16* bsrc = w2t + (size_t)e * C_DIM * F_DIM + (size_t)(c0 + bcol) * F_DIM
                    + kh * 1024 + 8 * (bcc ^ ((bcol >> 1) & 3));

  f32x16 acc[2][2] = {};
  int wr = (wid >> 1) * 64, wc = (wid & 1) * 64;

  f16 *a_c = &A_lds[0][0], *a_n = &A_lds[1][0], *a_f = &A_lds[2][0];
  f16 *b_c = &B_lds[0][0], *b_n = &B_lds[1][0], *b_f = &B_lds[2][0];

  glds16(asrc[0], a_c + wid * 512);
  glds16(asrc[1], a_c + (8 + wid) * 512);
  glds16(bsrc, b_c + wid * 512);
  glds16(asrc[0] + 32, a_n + wid * 512);
  glds16(asrc[1] + 32, a_n + (8 + wid) * 512);
  glds16(bsrc + 32, b_n + wid * 512);

  for (int tt = 0; tt < 30; ++tt) {
    asm volatile("s_waitcnt vmcnt(3)" ::: "memory");
    __builtin_amdgcn_s_barrier();
    asm volatile("" ::: "memory");
    int kn = (tt + 2) * 32;
    glds16(asrc[0] + kn, a_f + wid * 512);
    glds16(asrc[1] + kn, a_f + (8 + wid) * 512);
    glds16(bsrc + kn, b_f + wid * 512);
    DN_MFMA();
    ROT3(a_c, a_n, a_f); ROT3(b_c, b_n, b_f);
  }
  asm volatile("s_waitcnt vmcnt(3)" ::: "memory");
  __builtin_amdgcn_s_barrier();
  asm volatile("" ::: "memory");
  DN_MFMA();
  ROT3(a_c, a_n, a_f); ROT3(b_c, b_n, b_f);
  asm volatile("s_waitcnt vmcnt(0)" ::: "memory");
  __builtin_amdgcn_s_barrier();
  asm volatile("" ::: "memory");
  DN_MFMA();

#pragma unroll
  for (int mi = 0; mi < 2; ++mi)
#pragma unroll
    for (int ni = 0; ni < 2; ++ni)
#pragma unroll
      for (int i = 0; i < 16; ++i) {
        int rr = (i & 3) + 8 * (i >> 2) + 4 * fh;
        int lr = row0 + wr + mi * 32 + rr;
        if (lr < cnt)
          yb[(size_t)(off + lr) * C_DIM + c0 + wc + ni * 32 + ln31] = (f16)acc[mi][ni][i];
      }
}

// ---------------- combine ----------------
__global__ void combine_kernel(const f16* __restrict__ y0, const f16* __restrict__ y1,
                               const int* __restrict__ slot_of,
                               const float* __restrict__ topw,
                               float* __restrict__ out) {
  int n = blockIdx.x;
  int s0 = slot_of[2 * n], s1 = slot_of[2 * n + 1];
  float g0 = topw[2 * n], g1 = topw[2 * n + 1];
  int c = threadIdx.x * 4;
  f16x4 a0 = *(const f16x4*)(y0 + (size_t)s0 * C_DIM + c);
  f16x4 a1 = *(const f16x4*)(y1 + (size_t)s0 * C_DIM + c);
  f16x4 b0 = *(const f16x4*)(y0 + (size_t)s1 * C_DIM + c);
  f16x4 b1 = *(const f16x4*)(y1 + (size_t)s1 * C_DIM + c);
  f32x4 o;
#pragma unroll
  for (int i = 0; i < 4; ++i)
    o[i] = g0 * ((float)a0[i] + (float)a1[i]) + g1 * ((float)b0[i] + (float)b1[i]);
  *(f32x4*)(out + (size_t)n * C_DIM + c) = o;
}

extern "C" void kernel_launch(void* const* d_in, const int* in_sizes, int n_in,
                              void* d_out, int out_size, void* d_ws, size_t ws_size,
                              hipStream_t stream) {
  const float* x  = (const float*)d_in[0];
  const float* Wr = (const float*)d_in[1];
  const float* w1 = (const float*)d_in[2];
  const float* w3 = (const float*)d_in[3];
  const float* w2 = (const float*)d_in[4];
  float* out = (float*)d_out;
  char* ws = (char*)d_ws;

  int* counts    = (int*)(ws + WS_COUNTS);
  int* offsets   = (int*)(ws + WS_OFFSETS);
  int* cursor    = (int*)(ws + WS_CURSOR);
  int* topi      = (int*)(ws + WS_TOPI);
  float* topw    = (float*)(ws + WS_TOPW);
  int* rows_perm = (int*)(ws + WS_ROWS);
  int* slot_of   = (int*)(ws + WS_SLOT);
  f16* x16       = (f16*)(ws + WS_X16);
  f16* h_buf     = (f16*)(ws + WS_H);
  f16* y0        = (f16*)(ws + WS_Y0);
  f16* y1        = (f16*)(ws + WS_Y1);
  f16* w1t       = (f16*)(ws + WS_W1T);
  f16* w3t       = (f16*)(ws + WS_W3T);
  f16* w2t       = (f16*)(ws + WS_W2T);

  (void)hipMemsetAsync(ws, 0, 256, stream);
  wt_kernel<<<3072, 256, 0, stream>>>(w1, w3, w2, w1t, w3t, w2t);
  cvtx_kernel<<<N_TOK * C_DIM / 8 / 256, 256, 0, stream>>>(x, x16);
  router_kernel<<<N_TOK / 4, 256, 0, stream>>>(x, Wr, counts, topi, topw);
  scan_kernel<<<1, 64, 0, stream>>>(counts, offsets, cursor);
  scatter_kernel<<<N_TOK / 256, 256, 0, stream>>>(topi, cursor, rows_perm, slot_of);
  upproj_kernel<<<E_NUM * 128, 512, 0, stream>>>(
      x16, w1t, w3t, counts, offsets, rows_perm, h_buf);
  downproj_kernel<<<E_NUM * 128, 512, 0, stream>>>(
      h_buf, w2t, counts, offsets, y0, y1);
  combine_kernel<<<N_TOK, 256, 0, stream>>>(y0, y1, slot_of, topw, out);
}

// Round 9
// 234.738 us; speedup vs baseline: 1.1146x; 1.1146x over previous
//
#include <hip/hip_runtime.h>
#include <math.h>

typedef _Float16 f16;
typedef _Float16 f16x2 __attribute__((ext_vector_type(2)));
typedef _Float16 f16x4 __attribute__((ext_vector_type(4)));
typedef _Float16 f16x8 __attribute__((ext_vector_type(8)));
typedef __fp16 h16x2 __attribute__((ext_vector_type(2)));
typedef float f32x4 __attribute__((ext_vector_type(4)));
typedef float f32x16 __attribute__((ext_vector_type(16)));

#define N_TOK 2048
#define C_DIM 1024
#define E_NUM 8
#define F_DIM 2048
#define BM 256

// ws layout (bytes)
#define WS_COUNTS    0
#define WS_OFFSETS   64
#define WS_CURSOR    192
#define WS_TOPI      256
#define WS_TOPW      (WS_TOPI + 16384)
#define WS_ROWS      (WS_TOPW + 16384)
#define WS_SLOT      (WS_ROWS + 16384)
#define WS_X16       (1ull << 20)     // 4 MB
#define WS_H         (6ull << 20)     // 16.8 MB
#define WS_Y0        (23ull << 20)    // 8.4 MB
#define WS_Y1        (32ull << 20)    // 8.4 MB

__device__ __forceinline__ f16x2 pkrtz(float a, float b) {
  union { h16x2 h; f16x2 f; } u;
  u.h = __builtin_amdgcn_cvt_pkrtz(a, b);
  return u.f;
}

// ---------------- x fp32 -> fp16 ----------------
__global__ void cvtx_kernel(const float* __restrict__ x, f16* __restrict__ x16) {
  int i = (blockIdx.x * 256 + threadIdx.x) * 8;
  f32x4 a = *(const f32x4*)(x + i);
  f32x4 b = *(const f32x4*)(x + i + 4);
  union { f16x8 v; f16x2 h[4]; } u;
  u.h[0] = pkrtz(a[0], a[1]);
  u.h[1] = pkrtz(a[2], a[3]);
  u.h[2] = pkrtz(b[0], b[1]);
  u.h[3] = pkrtz(b[2], b[3]);
  *(f16x8*)(x16 + i) = u.v;
}

// ---------------- router ----------------
__global__ void router_kernel(const float* __restrict__ x, const float* __restrict__ Wr,
                              int* counts, int* topi, float* topw) {
  int tok = blockIdx.x * 4 + (threadIdx.x >> 6);
  int lane = threadIdx.x & 63;
  const float* xr = x + (size_t)tok * C_DIM;
  float xv[16];
#pragma unroll
  for (int i = 0; i < 16; ++i) xv[i] = xr[i * 64 + lane];
  float logit[E_NUM];
#pragma unroll
  for (int e = 0; e < E_NUM; ++e) {
    const float* wr = Wr + (size_t)e * C_DIM;
    float acc = 0.f;
#pragma unroll
    for (int i = 0; i < 16; ++i) acc += xv[i] * wr[i * 64 + lane];
#pragma unroll
    for (int s = 1; s < 64; s <<= 1) acc += __shfl_xor(acc, s, 64);
    logit[e] = acc;
  }
  if (lane == 0) {
    float m = logit[0];
#pragma unroll
    for (int e = 1; e < E_NUM; ++e) m = fmaxf(m, logit[e]);
    float p[E_NUM];
#pragma unroll
    for (int e = 0; e < E_NUM; ++e) p[e] = expf(logit[e] - m);
    float p0 = -1.f, p1 = -1.f;
    int i0 = 0, i1 = 0;
#pragma unroll
    for (int e = 0; e < E_NUM; ++e) {
      float v = p[e];
      if (v > p0) { p1 = p0; i1 = i0; p0 = v; i0 = e; }
      else if (v > p1) { p1 = v; i1 = e; }
    }
    float inv = 1.f / (p0 + p1);
    topi[2 * tok] = i0; topi[2 * tok + 1] = i1;
    topw[2 * tok] = p0 * inv; topw[2 * tok + 1] = p1 * inv;
    atomicAdd(&counts[i0], 1);
    atomicAdd(&counts[i1], 1);
  }
}

// ---------------- scan ----------------
__global__ void scan_kernel(const int* counts, int* offsets, int* cursor) {
  if (threadIdx.x == 0) {
    int o = 0;
    for (int e = 0; e < E_NUM; ++e) {
      offsets[e] = o; cursor[e] = o;
      o += counts[e];
    }
    offsets[E_NUM] = o;
  }
}

// ---------------- scatter ----------------
__global__ void scatter_kernel(const int* __restrict__ topi, int* cursor,
                               int* rows_perm, int* slot_of) {
  int n = blockIdx.x * blockDim.x + threadIdx.x;
  if (n >= N_TOK) return;
#pragma unroll
  for (int k = 0; k < 2; ++k) {
    int e = topi[2 * n + k];
    int pos = atomicAdd(&cursor[e], 1);
    rows_perm[pos] = n;
    slot_of[2 * n + k] = pos;
  }
}

#define BARRIER_PUB()                                          \
  asm volatile("s_waitcnt lgkmcnt(0)" ::: "memory");           \
  __builtin_amdgcn_s_barrier();                                \
  asm volatile("" ::: "memory");

// ================= up-proj: h = silu(x@w1)*(x@w3) =================
// 256x128 tile, BK=32, 8 waves each 64x64, 32x32x16 MFMA.
// A: global->VGPR direct (gathered rows, k-contiguous). B: fp32 strided
// loads + pkrtz + 1 ds_write_b128/thread into 2-buffered swizzled LDS.
#define UP_PACK_WRITE()                                                  \
  { union { f16x8 v; f16x2 h[4]; } u;                                    \
    u.h[0] = pkrtz(b1r[0], b1r[1]); u.h[1] = pkrtz(b1r[2], b1r[3]);      \
    u.h[2] = pkrtz(b1r[4], b1r[5]); u.h[3] = pkrtz(b1r[6], b1r[7]);      \
    *(f16x8*)&B1_lds[cur][bso] = u.v;                                    \
    u.h[0] = pkrtz(b3r[0], b3r[1]); u.h[1] = pkrtz(b3r[2], b3r[3]);      \
    u.h[2] = pkrtz(b3r[4], b3r[5]); u.h[3] = pkrtz(b3r[6], b3r[7]);      \
    *(f16x8*)&B3_lds[cur][bso] = u.v; }

#define UP_LOAD(ANXT, KN)                                                \
  { _Pragma("unroll") for (int j = 0; j < 8; ++j) {                      \
      b1r[j] = w1p[(size_t)(KN + j) * F_DIM];                            \
      b3r[j] = w3p[(size_t)(KN + j) * F_DIM]; }                          \
    _Pragma("unroll") for (int mi = 0; mi < 2; ++mi)                     \
      _Pragma("unroll") for (int kk = 0; kk < 2; ++kk)                   \
        ANXT[mi][kk] = *(const f16x8*)(aptr[mi] + (KN) + kk * 16 + fh * 8); }

#define UP_MFMA(ACUR)                                                    \
  { f16x8 bf[2][2];                                                      \
    _Pragma("unroll") for (int ni = 0; ni < 2; ++ni)                     \
      _Pragma("unroll") for (int kk = 0; kk < 2; ++kk) {                 \
        int col = wc + ni * 32 + ln31;                                   \
        int cell = (kk * 2 + fh) ^ ((col >> 1) & 3);                     \
        bf[ni][kk] = *(const f16x8*)&B1_lds[cur][col * 32 + cell * 8]; } \
    __builtin_amdgcn_s_setprio(1);                                       \
    _Pragma("unroll") for (int kk = 0; kk < 2; ++kk)                     \
      _Pragma("unroll") for (int mi = 0; mi < 2; ++mi)                   \
        _Pragma("unroll") for (int ni = 0; ni < 2; ++ni)                 \
          acc1[mi][ni] = __builtin_amdgcn_mfma_f32_32x32x16_f16(ACUR[mi][kk], bf[ni][kk], acc1[mi][ni], 0, 0, 0); \
    __builtin_amdgcn_s_setprio(0);                                       \
    _Pragma("unroll") for (int ni = 0; ni < 2; ++ni)                     \
      _Pragma("unroll") for (int kk = 0; kk < 2; ++kk) {                 \
        int col = wc + ni * 32 + ln31;                                   \
        int cell = (kk * 2 + fh) ^ ((col >> 1) & 3);                     \
        bf[ni][kk] = *(const f16x8*)&B3_lds[cur][col * 32 + cell * 8]; } \
    __builtin_amdgcn_s_setprio(1);                                       \
    _Pragma("unroll") for (int kk = 0; kk < 2; ++kk)                     \
      _Pragma("unroll") for (int mi = 0; mi < 2; ++mi)                   \
        _Pragma("unroll") for (int ni = 0; ni < 2; ++ni)                 \
          acc3[mi][ni] = __builtin_amdgcn_mfma_f32_32x32x16_f16(ACUR[mi][kk], bf[ni][kk], acc3[mi][ni], 0, 0, 0); \
    __builtin_amdgcn_s_setprio(0);                                       \
    cur ^= 1; }

#define UP_STEP(ACUR, ANXT, KN) \
  { UP_PACK_WRITE(); UP_LOAD(ANXT, KN); BARRIER_PUB(); UP_MFMA(ACUR); }

__launch_bounds__(512, 2)
__global__ void upproj_kernel(const f16* __restrict__ x16,
                              const float* __restrict__ w1,
                              const float* __restrict__ w3,
                              const int* __restrict__ counts,
                              const int* __restrict__ offsets,
                              const int* __restrict__ rows_perm,
                              f16* __restrict__ h_buf) {
  __shared__ __align__(16) f16 B1_lds[2][128 * 32];
  __shared__ __align__(16) f16 B3_lds[2][128 * 32];

  int bid = blockIdx.x;
  int e = bid & 7;            // expert-locked XCD
  int slot = bid >> 3;        // 0..127; valid blocks dense at low bids
  int fidx = slot & 15;
  int tile = slot >> 4;
  int cnt = counts[e];
  if (tile * BM >= cnt) return;
  int row0 = tile * BM;
  int off = offsets[e];
  int f0 = fidx * 128;
  int t = threadIdx.x, wid = t >> 6, lane = t & 63;
  int ln31 = lane & 31, fh = lane >> 5;
  int wr = (wid >> 1) * 64, wc = (wid & 1) * 64;

  // A row pointers (gathered), k-contiguous
  const f16* aptr[2];
#pragma unroll
  for (int mi = 0; mi < 2; ++mi) {
    int lr = row0 + wr + mi * 32 + ln31;
    if (lr > cnt - 1) lr = cnt - 1;
    aptr[mi] = x16 + (size_t)rows_perm[off + lr] * C_DIM;
  }

  int bcol = t & 127, kg = t >> 7;
  int bso = bcol * 32 + ((kg ^ ((bcol >> 1) & 3)) * 8);
  const size_t eb = (size_t)e * C_DIM * F_DIM;
  const float* w1p = w1 + eb + (size_t)(kg * 8) * F_DIM + f0 + bcol;
  const float* w3p = w3 + eb + (size_t)(kg * 8) * F_DIM + f0 + bcol;

  f32x16 acc1[2][2] = {};
  f32x16 acc3[2][2] = {};
  float b1r[8], b3r[8];
  f16x8 aX[2][2], aY[2][2];
  int cur = 0;

  UP_LOAD(aX, 0);
  for (int tp = 0; tp < 15; ++tp) {
    UP_STEP(aX, aY, (2 * tp + 1) * 32);
    UP_STEP(aY, aX, (2 * tp + 2) * 32);
  }
  UP_STEP(aX, aY, 31 * 32);
  { UP_PACK_WRITE(); BARRIER_PUB(); UP_MFMA(aY); }

#pragma unroll
  for (int mi = 0; mi < 2; ++mi)
#pragma unroll
    for (int ni = 0; ni < 2; ++ni)
#pragma unroll
      for (int i = 0; i < 16; ++i) {
        int rr = (i & 3) + 8 * (i >> 2) + 4 * fh;
        int lr = row0 + wr + mi * 32 + rr;
        if (lr < cnt) {
          float v1 = acc1[mi][ni][i], v3 = acc3[mi][ni][i];
          float hval = v1 / (1.f + expf(-v1)) * v3;
          h_buf[(size_t)(off + lr) * F_DIM + f0 + wc + ni * 32 + ln31] = (f16)hval;
        }
      }
}

// ================= down-proj =================
#define DN_PACK_WRITE()                                                  \
  { union { f16x8 v; f16x2 h[4]; } u;                                    \
    u.h[0] = pkrtz(br[0], br[1]); u.h[1] = pkrtz(br[2], br[3]);          \
    u.h[2] = pkrtz(br[4], br[5]); u.h[3] = pkrtz(br[6], br[7]);          \
    *(f16x8*)&B_lds[cur][bso] = u.v; }

#define DN_LOAD(ANXT, KN)                                                \
  { _Pragma("unroll") for (int j = 0; j < 8; ++j)                        \
      br[j] = w2p[(size_t)(KN + j) * C_DIM];                             \
    _Pragma("unroll") for (int mi = 0; mi < 2; ++mi)                     \
      _Pragma("unroll") for (int kk = 0; kk < 2; ++kk)                   \
        ANXT[mi][kk] = *(const f16x8*)(aptr[mi] + (KN) + kk * 16 + fh * 8); }

#define DN_MFMA(ACUR)                                                    \
  { f16x8 bf[2][2];                                                      \
    _Pragma("unroll") for (int ni = 0; ni < 2; ++ni)                     \
      _Pragma("unroll") for (int kk = 0; kk < 2; ++kk) {                 \
        int col = wc + ni * 32 + ln31;                                   \
        int cell = (kk * 2 + fh) ^ ((col >> 1) & 3);                     \
        bf[ni][kk] = *(const f16x8*)&B_lds[cur][col * 32 + cell * 8]; }  \
    __builtin_amdgcn_s_setprio(1);                                       \
    _Pragma("unroll") for (int kk = 0; kk < 2; ++kk)                     \
      _Pragma("unroll") for (int mi = 0; mi < 2; ++mi)                   \
        _Pragma("unroll") for (int ni = 0; ni < 2; ++ni)                 \
          acc[mi][ni] = __builtin_amdgcn_mfma_f32_32x32x16_f16(ACUR[mi][kk], bf[ni][kk], acc[mi][ni], 0, 0, 0); \
    __builtin_amdgcn_s_setprio(0);                                       \
    cur ^= 1; }

#define DN_STEP(ACUR, ANXT, KN) \
  { DN_PACK_WRITE(); DN_LOAD(ANXT, KN); BARRIER_PUB(); DN_MFMA(ACUR); }

__launch_bounds__(512, 2)
__global__ void downproj_kernel(const f16* __restrict__ h_buf,
                                const float* __restrict__ w2,
                                const int* __restrict__ counts,
                                const int* __restrict__ offsets,
                                f16* __restrict__ y0,
                                f16* __restrict__ y1) {
  __shared__ __align__(16) f16 B_lds[2][128 * 32];

  int bid = blockIdx.x;
  int e = bid & 7;
  int slot = bid >> 3;         // 0..127
  int cidx = slot & 7;
  int kh = (slot >> 3) & 1;
  int tile = slot >> 4;
  int cnt = counts[e];
  if (tile * BM >= cnt) return;
  f16* yb = kh ? y1 : y0;
  int row0 = tile * BM;
  int off = offsets[e];
  int c0 = cidx * 128;
  int t = threadIdx.x, wid = t >> 6, lane = t & 63;
  int ln31 = lane & 31, fh = lane >> 5;
  int wr = (wid >> 1) * 64, wc = (wid & 1) * 64;

  const f16* aptr[2];
#pragma unroll
  for (int mi = 0; mi < 2; ++mi) {
    int lr = row0 + wr + mi * 32 + ln31;
    if (lr > cnt - 1) lr = cnt - 1;
    aptr[mi] = h_buf + (size_t)(off + lr) * F_DIM + kh * 1024;
  }

  int bcol = t & 127, kg = t >> 7;
  int bso = bcol * 32 + ((kg ^ ((bcol >> 1) & 3)) * 8);
  const float* w2p = w2 + (size_t)e * F_DIM * C_DIM
                     + (size_t)(kh * 1024 + kg * 8) * C_DIM + c0 + bcol;

  f32x16 acc[2][2] = {};
  float br[8];
  f16x8 aX[2][2], aY[2][2];
  int cur = 0;

  DN_LOAD(aX, 0);
  for (int tp = 0; tp < 15; ++tp) {
    DN_STEP(aX, aY, (2 * tp + 1) * 32);
    DN_STEP(aY, aX, (2 * tp + 2) * 32);
  }
  DN_STEP(aX, aY, 31 * 32);
  { DN_PACK_WRITE(); BARRIER_PUB(); DN_MFMA(aY); }

#pragma unroll
  for (int mi = 0; mi < 2; ++mi)
#pragma unroll
    for (int ni = 0; ni < 2; ++ni)
#pragma unroll
      for (int i = 0; i < 16; ++i) {
        int rr = (i & 3) + 8 * (i >> 2) + 4 * fh;
        int lr = row0 + wr + mi * 32 + rr;
        if (lr < cnt)
          yb[(size_t)(off + lr) * C_DIM + c0 + wc + ni * 32 + ln31] = (f16)acc[mi][ni][i];
      }
}

// ---------------- combine ----------------
__global__ void combine_kernel(const f16* __restrict__ y0, const f16* __restrict__ y1,
                               const int* __restrict__ slot_of,
                               const float* __restrict__ topw,
                               float* __restrict__ out) {
  int n = blockIdx.x;
  int s0 = slot_of[2 * n], s1 = slot_of[2 * n + 1];
  float g0 = topw[2 * n], g1 = topw[2 * n + 1];
  int c = threadIdx.x * 4;
  f16x4 a0 = *(const f16x4*)(y0 + (size_t)s0 * C_DIM + c);
  f16x4 a1 = *(const f16x4*)(y1 + (size_t)s0 * C_DIM + c);
  f16x4 b0 = *(const f16x4*)(y0 + (size_t)s1 * C_DIM + c);
  f16x4 b1 = *(const f16x4*)(y1 + (size_t)s1 * C_DIM + c);
  f32x4 o;
#pragma unroll
  for (int i = 0; i < 4; ++i)
    o[i] = g0 * ((float)a0[i] + (float)a1[i]) + g1 * ((float)b0[i] + (float)b1[i]);
  *(f32x4*)(out + (size_t)n * C_DIM + c) = o;
}

extern "C" void kernel_launch(void* const* d_in, const int* in_sizes, int n_in,
                              void* d_out, int out_size, void* d_ws, size_t ws_size,
                              hipStream_t stream) {
  const float* x  = (const float*)d_in[0];
  const float* Wr = (const float*)d_in[1];
  const float* w1 = (const float*)d_in[2];
  const float* w3 = (const float*)d_in[3];
  const float* w2 = (const float*)d_in[4];
  float* out = (float*)d_out;
  char* ws = (char*)d_ws;

  int* counts    = (int*)(ws + WS_COUNTS);
  int* offsets   = (int*)(ws + WS_OFFSETS);
  int* cursor    = (int*)(ws + WS_CURSOR);
  int* topi      = (int*)(ws + WS_TOPI);
  float* topw    = (float*)(ws + WS_TOPW);
  int* rows_perm = (int*)(ws + WS_ROWS);
  int* slot_of   = (int*)(ws + WS_SLOT);
  f16* x16       = (f16*)(ws + WS_X16);
  f16* h_buf     = (f16*)(ws + WS_H);
  f16* y0        = (f16*)(ws + WS_Y0);
  f16* y1        = (f16*)(ws + WS_Y1);

  (void)hipMemsetAsync(ws, 0, 256, stream);
  cvtx_kernel<<<N_TOK * C_DIM / 8 / 256, 256, 0, stream>>>(x, x16);
  router_kernel<<<N_TOK / 4, 256, 0, stream>>>(x, Wr, counts, topi, topw);
  scan_kernel<<<1, 64, 0, stream>>>(counts, offsets, cursor);
  scatter_kernel<<<N_TOK / 256, 256, 0, stream>>>(topi, cursor, rows_perm, slot_of);
  upproj_kernel<<<E_NUM * 128, 512, 0, stream>>>(
      x16, w1, w3, counts, offsets, rows_perm, h_buf);
  downproj_kernel<<<E_NUM * 128, 512, 0, stream>>>(
      h_buf, w2, counts, offsets, y0, y1);
  combine_kernel<<<N_TOK, 256, 0, stream>>>(y0, y1, slot_of, topw, out);
}

// Round 11
// 220.574 us; speedup vs baseline: 1.1862x; 1.0642x over previous
//
#include <hip/hip_runtime.h>
#include <math.h>

typedef _Float16 f16;
typedef _Float16 f16x2 __attribute__((ext_vector_type(2)));
typedef _Float16 f16x4 __attribute__((ext_vector_type(4)));
typedef _Float16 f16x8 __attribute__((ext_vector_type(8)));
typedef __fp16 h16x2 __attribute__((ext_vector_type(2)));
typedef float f32x4 __attribute__((ext_vector_type(4)));
typedef float f32x16 __attribute__((ext_vector_type(16)));

#define N_TOK 2048
#define C_DIM 1024
#define E_NUM 8
#define F_DIM 2048
#define BM 128

// ws layout (bytes)
#define WS_COUNTS    0
#define WS_OFFSETS   64
#define WS_CURSOR    192
#define WS_TOPI      256
#define WS_TOPW      (WS_TOPI + 16384)
#define WS_ROWS      (WS_TOPW + 16384)
#define WS_SLOT      (WS_ROWS + 16384)
#define WS_X16       (1ull << 20)     // 4 MB
#define WS_H         (6ull << 20)     // 16.8 MB
#define WS_Y0        (23ull << 20)    // 8.4 MB
#define WS_Y1        (32ull << 20)    // 8.4 MB

__device__ __forceinline__ void glds16(const void* g, void* l) {
  __builtin_amdgcn_global_load_lds((const __attribute__((address_space(1))) void*)g,
                                   (__attribute__((address_space(3))) void*)l, 16, 0, 0);
}

__device__ __forceinline__ f16x2 pkrtz(float a, float b) {
  union { h16x2 h; f16x2 f; } u;
  u.h = __builtin_amdgcn_cvt_pkrtz(a, b);
  return u.f;
}

// ---------------- x fp32 -> fp16 ----------------
__global__ void cvtx_kernel(const float* __restrict__ x, f16* __restrict__ x16) {
  int i = (blockIdx.x * 256 + threadIdx.x) * 8;
  f32x4 a = *(const f32x4*)(x + i);
  f32x4 b = *(const f32x4*)(x + i + 4);
  union { f16x8 v; f16x2 h[4]; } u;
  u.h[0] = pkrtz(a[0], a[1]);
  u.h[1] = pkrtz(a[2], a[3]);
  u.h[2] = pkrtz(b[0], b[1]);
  u.h[3] = pkrtz(b[2], b[3]);
  *(f16x8*)(x16 + i) = u.v;
}

// ---------------- router ----------------
__global__ void router_kernel(const float* __restrict__ x, const float* __restrict__ Wr,
                              int* counts, int* topi, float* topw) {
  int tok = blockIdx.x * 4 + (threadIdx.x >> 6);
  int lane = threadIdx.x & 63;
  const float* xr = x + (size_t)tok * C_DIM;
  float xv[16];
#pragma unroll
  for (int i = 0; i < 16; ++i) xv[i] = xr[i * 64 + lane];
  float logit[E_NUM];
#pragma unroll
  for (int e = 0; e < E_NUM; ++e) {
    const float* wr = Wr + (size_t)e * C_DIM;
    float acc = 0.f;
#pragma unroll
    for (int i = 0; i < 16; ++i) acc += xv[i] * wr[i * 64 + lane];
#pragma unroll
    for (int s = 1; s < 64; s <<= 1) acc += __shfl_xor(acc, s, 64);
    logit[e] = acc;
  }
  if (lane == 0) {
    float m = logit[0];
#pragma unroll
    for (int e = 1; e < E_NUM; ++e) m = fmaxf(m, logit[e]);
    float p[E_NUM];
#pragma unroll
    for (int e = 0; e < E_NUM; ++e) p[e] = expf(logit[e] - m);
    float p0 = -1.f, p1 = -1.f;
    int i0 = 0, i1 = 0;
#pragma unroll
    for (int e = 0; e < E_NUM; ++e) {
      float v = p[e];
      if (v > p0) { p1 = p0; i1 = i0; p0 = v; i0 = e; }
      else if (v > p1) { p1 = v; i1 = e; }
    }
    float inv = 1.f / (p0 + p1);
    topi[2 * tok] = i0; topi[2 * tok + 1] = i1;
    topw[2 * tok] = p0 * inv; topw[2 * tok + 1] = p1 * inv;
    atomicAdd(&counts[i0], 1);
    atomicAdd(&counts[i1], 1);
  }
}

// ---------------- scan ----------------
__global__ void scan_kernel(const int* counts, int* offsets, int* cursor) {
  if (threadIdx.x == 0) {
    int o = 0;
    for (int e = 0; e < E_NUM; ++e) {
      offsets[e] = o; cursor[e] = o;
      o += counts[e];
    }
    offsets[E_NUM] = o;
  }
}

// ---------------- scatter ----------------
__global__ void scatter_kernel(const int* __restrict__ topi, int* cursor,
                               int* rows_perm, int* slot_of) {
  int n = blockIdx.x * blockDim.x + threadIdx.x;
  if (n >= N_TOK) return;
#pragma unroll
  for (int k = 0; k < 2; ++k) {
    int e = topi[2 * n + k];
    int pos = atomicAdd(&cursor[e], 1);
    rows_perm[pos] = n;
    slot_of[2 * n + k] = pos;
  }
}

#define ROT3(P0, P1, P2) { f16* _t = P0; P0 = P1; P1 = P2; P2 = _t; }

// ================= up-proj: h = silu(x@w1)*(x@w3) =================
// 128x64 tile, BK=32, 4 waves (wave 64x32), 32x32x16 MFMA, 3 blocks/CU.
// A: glds (swizzled src, 3-buf, depth-2). B: strided fp32 -> pkrtz ->
// lane-linear LDS [kcell][col] (0 conflicts), reg banks at depth-2.
#define UP_ISSUE(B1R, B3R, KN)                                     \
  { _Pragma("unroll") for (int j = 0; j < 8; ++j) {                \
      B1R[j] = w1p[(size_t)((KN) + j) * F_DIM];                    \
      B3R[j] = w3p[(size_t)((KN) + j) * F_DIM]; }                  \
    glds16(asrc[0] + (KN), a_f + (wid * 64) * 8);                  \
    glds16(asrc[1] + (KN), a_f + (256 + wid * 64) * 8); }

#define UP_STEP(B1R, B3R, BUF, T, ISSUE, VM)                                   \
  { asm volatile("s_waitcnt vmcnt(" #VM ")" ::: "memory");                     \
    { union { f16x8 v; f16x2 h[4]; } u;                                        \
      u.h[0] = pkrtz(B1R[0], B1R[1]); u.h[1] = pkrtz(B1R[2], B1R[3]);          \
      u.h[2] = pkrtz(B1R[4], B1R[5]); u.h[3] = pkrtz(B1R[6], B1R[7]);          \
      *(f16x8*)(B1_lds[BUF] + t * 8) = u.v;                                    \
      u.h[0] = pkrtz(B3R[0], B3R[1]); u.h[1] = pkrtz(B3R[2], B3R[3]);          \
      u.h[2] = pkrtz(B3R[4], B3R[5]); u.h[3] = pkrtz(B3R[6], B3R[7]);          \
      *(f16x8*)(B3_lds[BUF] + t * 8) = u.v; }                                  \
    asm volatile("s_waitcnt lgkmcnt(0)" ::: "memory");                         \
    __builtin_amdgcn_s_barrier();                                              \
    asm volatile("" ::: "memory");                                             \
    if (ISSUE) { UP_ISSUE(B1R, B3R, ((T) + 2) * 32); }                         \
    { f16x8 af[2][2], bf[2];                                                   \
      _Pragma("unroll") for (int mi = 0; mi < 2; ++mi)                         \
        _Pragma("unroll") for (int kk = 0; kk < 2; ++kk) {                     \
          int row = wr + mi * 32 + ln31;                                       \
          int cell = (kk * 2 + fh) ^ ((row >> 1) & 3);                         \
          af[mi][kk] = *(const f16x8*)&a_c[row * 32 + cell * 8]; }             \
      _Pragma("unroll") for (int kk = 0; kk < 2; ++kk)                         \
        bf[kk] = *(const f16x8*)(B1_lds[BUF] + ((kk * 2 + fh) * 64 + wc + ln31) * 8); \
      __builtin_amdgcn_s_setprio(1);                                           \
      _Pragma("unroll") for (int kk = 0; kk < 2; ++kk)                         \
        _Pragma("unroll") for (int mi = 0; mi < 2; ++mi)                       \
          acc1[mi] = __builtin_amdgcn_mfma_f32_32x32x16_f16(af[mi][kk], bf[kk], acc1[mi], 0, 0, 0); \
      __builtin_amdgcn_s_setprio(0);                                           \
      _Pragma("unroll") for (int kk = 0; kk < 2; ++kk)                         \
        bf[kk] = *(const f16x8*)(B3_lds[BUF] + ((kk * 2 + fh) * 64 + wc + ln31) * 8); \
      __builtin_amdgcn_s_setprio(1);                                           \
      _Pragma("unroll") for (int kk = 0; kk < 2; ++kk)                         \
        _Pragma("unroll") for (int mi = 0; mi < 2; ++mi)                       \
          acc3[mi] = __builtin_amdgcn_mfma_f32_32x32x16_f16(af[mi][kk], bf[kk], acc3[mi], 0, 0, 0); \
      __builtin_amdgcn_s_setprio(0); }                                         \
    ROT3(a_c, a_n, a_f); }

__launch_bounds__(256, 3)
__global__ void upproj_kernel(const f16* __restrict__ x16,
                              const float* __restrict__ w1,
                              const float* __restrict__ w3,
                              const int* __restrict__ counts,
                              const int* __restrict__ offsets,
                              const int* __restrict__ rows_perm,
                              f16* __restrict__ h_buf) {
  __shared__ __align__(16) f16 A_lds[3][BM * 32];
  __shared__ __align__(16) f16 B1_lds[2][4 * 64 * 8];
  __shared__ __align__(16) f16 B3_lds[2][4 * 64 * 8];

  int bid = blockIdx.x;
  int e = bid & 7;            // expert-locked XCD
  int slot = bid >> 3;        // 0..511
  int fidx = slot & 31;       // F/64
  int tile = slot >> 5;       // 0..15 -> capacity 16*128 = 2048 rows/expert
  int cnt = counts[e];
  if (tile * BM >= cnt) return;
  int row0 = tile * BM;
  int off = offsets[e];
  int f0 = fidx * 64;
  int t = threadIdx.x, wid = t >> 6, lane = t & 63;
  int ln31 = lane & 31, fh = lane >> 5;
  int wr = (wid >> 1) * 64, wc = (wid & 1) * 32;

  // A glds sources: 512 chunks (128 rows x 4 cells), 2/thread, swizzled cell
  const f16* asrc[2];
#pragma unroll
  for (int p = 0; p < 2; ++p) {
    int c = p * 256 + t;
    int row = c >> 2, cc = c & 3;
    int lr = row0 + row; if (lr > cnt - 1) lr = cnt - 1;
    asrc[p] = x16 + (size_t)rows_perm[off + lr] * C_DIM + 8 * (cc ^ ((row >> 1) & 3));
  }

  // B: thread t -> col = t&63, kcell = t>>6 (8 k-consecutive f16 per write)
  const size_t eb = (size_t)e * C_DIM * F_DIM;
  const float* w1p = w1 + eb + (size_t)((t >> 6) * 8) * F_DIM + f0 + (t & 63);
  const float* w3p = w3 + eb + (size_t)((t >> 6) * 8) * F_DIM + f0 + (t & 63);

  f32x16 acc1[2] = {};
  f32x16 acc3[2] = {};
  float b1X[8], b3X[8], b1Y[8], b3Y[8];

  f16 *a_c = &A_lds[0][0], *a_n = &A_lds[1][0], *a_f = &A_lds[2][0];

  // prologue: set0 -> bankX/a_c, set1 -> bankY/a_n
  { f16* sv = a_f; a_f = a_c; UP_ISSUE(b1X, b3X, 0); a_f = a_n; UP_ISSUE(b1Y, b3Y, 32); a_f = sv; }

  for (int tp = 0; tp < 15; ++tp) {
    UP_STEP(b1X, b3X, 0, 2 * tp, 1, 18);
    UP_STEP(b1Y, b3Y, 1, 2 * tp + 1, 1, 18);
  }
  UP_STEP(b1X, b3X, 0, 30, 0, 18);
  UP_STEP(b1Y, b3Y, 1, 31, 0, 0);

#pragma unroll
  for (int mi = 0; mi < 2; ++mi)
#pragma unroll
    for (int i = 0; i < 16; ++i) {
      int rr = (i & 3) + 8 * (i >> 2) + 4 * fh;
      int lr = row0 + wr + mi * 32 + rr;
      if (lr < cnt) {
        float v1 = acc1[mi][i], v3 = acc3[mi][i];
        float hval = v1 / (1.f + expf(-v1)) * v3;
        h_buf[(size_t)(off + lr) * F_DIM + f0 + wc + ln31] = (f16)hval;
      }
    }
}

// ================= down-proj =================
#define DN_ISSUE(BR, KN)                                           \
  { _Pragma("unroll") for (int j = 0; j < 8; ++j)                  \
      BR[j] = w2p[(size_t)((KN) + j) * C_DIM];                     \
    glds16(asrc[0] + (KN), a_f + (wid * 64) * 8);                  \
    glds16(asrc[1] + (KN), a_f + (256 + wid * 64) * 8); }

#define DN_STEP(BR, BUF, T, ISSUE, VM)                                         \
  { asm volatile("s_waitcnt vmcnt(" #VM ")" ::: "memory");                     \
    { union { f16x8 v; f16x2 h[4]; } u;                                        \
      u.h[0] = pkrtz(BR[0], BR[1]); u.h[1] = pkrtz(BR[2], BR[3]);              \
      u.h[2] = pkrtz(BR[4], BR[5]); u.h[3] = pkrtz(BR[6], BR[7]);              \
      *(f16x8*)(B_lds[BUF] + t * 8) = u.v; }                                   \
    asm volatile("s_waitcnt lgkmcnt(0)" ::: "memory");                         \
    __builtin_amdgcn_s_barrier();                                              \
    asm volatile("" ::: "memory");                                             \
    if (ISSUE) { DN_ISSUE(BR, ((T) + 2) * 32); }                               \
    { f16x8 af[2][2], bf[2];                                                   \
      _Pragma("unroll") for (int mi = 0; mi < 2; ++mi)                         \
        _Pragma("unroll") for (int kk = 0; kk < 2; ++kk) {                     \
          int row = wr + mi * 32 + ln31;                                       \
          int cell = (kk * 2 + fh) ^ ((row >> 1) & 3);                         \
          af[mi][kk] = *(const f16x8*)&a_c[row * 32 + cell * 8]; }             \
      _Pragma("unroll") for (int kk = 0; kk < 2; ++kk)                         \
        bf[kk] = *(const f16x8*)(B_lds[BUF] + ((kk * 2 + fh) * 64 + wc + ln31) * 8); \
      __builtin_amdgcn_s_setprio(1);                                           \
      _Pragma("unroll") for (int kk = 0; kk < 2; ++kk)                         \
        _Pragma("unroll") for (int mi = 0; mi < 2; ++mi)                       \
          acc[mi] = __builtin_amdgcn_mfma_f32_32x32x16_f16(af[mi][kk], bf[kk], acc[mi], 0, 0, 0); \
      __builtin_amdgcn_s_setprio(0); }                                         \
    ROT3(a_c, a_n, a_f); }

__launch_bounds__(256, 3)
__global__ void downproj_kernel(const f16* __restrict__ h_buf,
                                const float* __restrict__ w2,
                                const int* __restrict__ counts,
                                const int* __restrict__ offsets,
                                f16* __restrict__ y0,
                                f16* __restrict__ y1) {
  __shared__ __align__(16) f16 A_lds[3][BM * 32];
  __shared__ __align__(16) f16 B_lds[2][4 * 64 * 8];

  int bid = blockIdx.x;
  int e = bid & 7;
  int slot = bid >> 3;         // 0..511
  int cidx = slot & 15;        // C/64
  int kh = (slot >> 4) & 1;
  int tile = slot >> 5;        // 0..15 -> capacity 2048 rows/expert
  int cnt = counts[e];
  if (tile * BM >= cnt) return;
  f16* yb = kh ? y1 : y0;
  int row0 = tile * BM;
  int off = offsets[e];
  int c0 = cidx * 64;
  int t = threadIdx.x, wid = t >> 6, lane = t & 63;
  int ln31 = lane & 31, fh = lane >> 5;
  int wr = (wid >> 1) * 64, wc = (wid & 1) * 32;

  const f16* asrc[2];
#pragma unroll
  for (int p = 0; p < 2; ++p) {
    int c = p * 256 + t;
    int row = c >> 2, cc = c & 3;
    int lr = row0 + row; if (lr > cnt - 1) lr = cnt - 1;
    asrc[p] = h_buf + (size_t)(off + lr) * F_DIM + kh * 1024 + 8 * (cc ^ ((row >> 1) & 3));
  }

  const float* w2p = w2 + (size_t)e * F_DIM * C_DIM
                     + (size_t)(kh * 1024 + (t >> 6) * 8) * C_DIM + c0 + (t & 63);

  f32x16 acc[2] = {};
  float bX[8], bY[8];

  f16 *a_c = &A_lds[0][0], *a_n = &A_lds[1][0], *a_f = &A_lds[2][0];

  { f16* sv = a_f; a_f = a_c; DN_ISSUE(bX, 0); a_f = a_n; DN_ISSUE(bY, 32); a_f = sv; }

  for (int tp = 0; tp < 15; ++tp) {
    DN_STEP(bX, 0, 2 * tp, 1, 10);
    DN_STEP(bY, 1, 2 * tp + 1, 1, 10);
  }
  DN_STEP(bX, 0, 30, 0, 10);
  DN_STEP(bY, 1, 31, 0, 0);

#pragma unroll
  for (int mi = 0; mi < 2; ++mi)
#pragma unroll
    for (int i = 0; i < 16; ++i) {
      int rr = (i & 3) + 8 * (i >> 2) + 4 * fh;
      int lr = row0 + wr + mi * 32 + rr;
      if (lr < cnt)
        yb[(size_t)(off + lr) * C_DIM + c0 + wc + ln31] = (f16)acc[mi][i];
    }
}

// ---------------- combine ----------------
__global__ void combine_kernel(const f16* __restrict__ y0, const f16* __restrict__ y1,
                               const int* __restrict__ slot_of,
                               const float* __restrict__ topw,
                               float* __restrict__ out) {
  int n = blockIdx.x;
  int s0 = slot_of[2 * n], s1 = slot_of[2 * n + 1];
  float g0 = topw[2 * n], g1 = topw[2 * n + 1];
  int c = threadIdx.x * 4;
  f16x4 a0 = *(const f16x4*)(y0 + (size_t)s0 * C_DIM + c);
  f16x4 a1 = *(const f16x4*)(y1 + (size_t)s0 * C_DIM + c);
  f16x4 b0 = *(const f16x4*)(y0 + (size_t)s1 * C_DIM + c);
  f16x4 b1 = *(const f16x4*)(y1 + (size_t)s1 * C_DIM + c);
  f32x4 o;
#pragma unroll
  for (int i = 0; i < 4; ++i)
    o[i] = g0 * ((float)a0[i] + (float)a1[i]) + g1 * ((float)b0[i] + (float)b1[i]);
  *(f32x4*)(out + (size_t)n * C_DIM + c) = o;
}

extern "C" void kernel_launch(void* const* d_in, const int* in_sizes, int n_in,
                              void* d_out, int out_size, void* d_ws, size_t ws_size,
                              hipStream_t stream) {
  const float* x  = (const float*)d_in[0];
  const float* Wr = (const float*)d_in[1];
  const float* w1 = (const float*)d_in[2];
  const float* w3 = (const float*)d_in[3];
  const float* w2 = (const float*)d_in[4];
  float* out = (float*)d_out;
  char* ws = (char*)d_ws;

  int* counts    = (int*)(ws + WS_COUNTS);
  int* offsets   = (int*)(ws + WS_OFFSETS);
  int* cursor    = (int*)(ws + WS_CURSOR);
  int* topi      = (int*)(ws + WS_TOPI);
  float* topw    = (float*)(ws + WS_TOPW);
  int* rows_perm = (int*)(ws + WS_ROWS);
  int* slot_of   = (int*)(ws + WS_SLOT);
  f16* x16       = (f16*)(ws + WS_X16);
  f16* h_buf     = (f16*)(ws + WS_H);
  f16* y0        = (f16*)(ws + WS_Y0);
  f16* y1        = (f16*)(ws + WS_Y1);

  (void)hipMemsetAsync(ws, 0, 256, stream);
  cvtx_kernel<<<N_TOK * C_DIM / 8 / 256, 256, 0, stream>>>(x, x16);
  router_kernel<<<N_TOK / 4, 256, 0, stream>>>(x, Wr, counts, topi, topw);
  scan_kernel<<<1, 64, 0, stream>>>(counts, offsets, cursor);
  scatter_kernel<<<N_TOK / 256, 256, 0, stream>>>(topi, cursor, rows_perm, slot_of);
  upproj_kernel<<<E_NUM * 512, 256, 0, stream>>>(
      x16, w1, w3, counts, offsets, rows_perm, h_buf);
  downproj_kernel<<<E_NUM * 512, 256, 0, stream>>>(
      h_buf, w2, counts, offsets, y0, y1);
  combine_kernel<<<N_TOK, 256, 0, stream>>>(y0, y1, slot_of, topw, out);
}